// Round 5
// baseline (10115.450 us; speedup 1.0000x reference)
//
#include <hip/hip_runtime.h>
#include <math.h>

#define TT 2048
#define EE 512
#define HDD 512
#define TAGS 32
#define STARTT 30
#define STOPP 31
#define NEGV -10000.0f
#define VCH 256    // viterbi feats LDS chunk (steps)
#define SENT 0xFFFFFFFFu   // hs sentinel: -NaN bit pattern, unreachable for finite h

// ---------------- embedding gather: x[t][:] = emb[sent[t]][:] ----------------
__global__ void k_gather(const int* __restrict__ sent, const float* __restrict__ emb,
                         float* __restrict__ x) {
    int t = blockIdx.x;
    int e4 = threadIdx.x;  // 128 threads * float4 = 512 floats
    const float4* src = (const float4*)(emb + (size_t)sent[t] * EE);
    ((float4*)(x + (size_t)t * EE))[e4] = src[e4];
}

// ------- xg[dir][t][n] = sum_k x[t][k]*w_ih[n][k] + b[n]  (A@B^T GEMM) -------
__global__ __launch_bounds__(256) void k_xgemm(const float* __restrict__ x,
        const float* __restrict__ wf, const float* __restrict__ wb,
        const float* __restrict__ bf, const float* __restrict__ bb,
        float* __restrict__ xg) {
    const int dir = blockIdx.z;
    const float* __restrict__ w    = dir ? wb : wf;
    const float* __restrict__ bias = dir ? bb : bf;
    const int tb = blockIdx.y * 64;
    const int nb = blockIdx.x * 64;
    __shared__ float As[64][17];
    __shared__ float Bs[64][17];
    const int tid = threadIdx.x;
    const int lr = tid >> 2;
    const int lc = (tid & 3) * 4;
    const int ty = tid >> 4;
    const int tx = tid & 15;
    float acc[4][4] = {};
    for (int k0 = 0; k0 < EE; k0 += 16) {
        float4 av = *(const float4*)(x + (size_t)(tb + lr) * EE + k0 + lc);
        float4 bv = *(const float4*)(w + (size_t)(nb + lr) * EE + k0 + lc);
        As[lr][lc+0] = av.x; As[lr][lc+1] = av.y; As[lr][lc+2] = av.z; As[lr][lc+3] = av.w;
        Bs[lr][lc+0] = bv.x; Bs[lr][lc+1] = bv.y; Bs[lr][lc+2] = bv.z; Bs[lr][lc+3] = bv.w;
        __syncthreads();
        #pragma unroll
        for (int kk = 0; kk < 16; ++kk) {
            float a[4], b[4];
            #pragma unroll
            for (int i = 0; i < 4; ++i) a[i] = As[ty*4+i][kk];
            #pragma unroll
            for (int j = 0; j < 4; ++j) b[j] = Bs[tx*4+j][kk];
            #pragma unroll
            for (int i = 0; i < 4; ++i)
                #pragma unroll
                for (int j = 0; j < 4; ++j)
                    acc[i][j] += a[i] * b[j];
        }
        __syncthreads();
    }
    #pragma unroll
    for (int i = 0; i < 4; ++i) {
        float4 o;
        o.x = acc[i][0] + bias[nb + tx*4 + 0];
        o.y = acc[i][1] + bias[nb + tx*4 + 1];
        o.z = acc[i][2] + bias[nb + tx*4 + 2];
        o.w = acc[i][3] + bias[nb + tx*4 + 3];
        *(float4*)(xg + ((size_t)dir*TT + tb + ty*4 + i) * 2048 + nb + tx*4) = o;
    }
}

__device__ __forceinline__ float fsig(float x) {
    return __builtin_amdgcn_rcpf(1.f + __expf(-x));
}
__device__ __forceinline__ float ftanh(float x) {
    return 2.f * __builtin_amdgcn_rcpf(1.f + __expf(-2.f * x)) - 1.f;
}

// ---------------- bidirectional LSTM recurrence (wave-autonomous v2) --------
// grid (64, 2) x 256 = 256 waves/dir. Each wave owns 2 hidden units:
// lane = unit*32 + gate*8 + seg (8-way k split, 64 floats/lane -> 16 float4
// weights, dot uses 4 independent accumulators: serial FMA chain ~80 cyc
// instead of 512). Cross-wave sync is data-flagged (hs sentinel 0xFF) with a
// PRE-ARMED poll: next-step loads are issued at the end of each iteration
// (right after the h store), own units substituted from registers, so the
// top-of-loop check usually hits and retries overlap the store-ack.
// No __syncthreads anywhere in the step loop.
__global__ __launch_bounds__(256, 1) void k_lstm(const float* __restrict__ xg,
        const float* __restrict__ whhf, const float* __restrict__ whhb,
        const float* __restrict__ h0, const float* __restrict__ c0,
        float* __restrict__ hs) {
    const int dir = blockIdx.y;
    const float* __restrict__ whh = dir ? whhb : whhf;
    const int tid    = threadIdx.x;
    const int lane   = tid & 63;
    const int waveid = tid >> 6;
    const int seg    = lane & 7;         // k segment (64 floats)
    const int gate   = (lane >> 3) & 3;  // i,f,g,o
    const int unit   = lane >> 5;        // 0..1
    const int W      = blockIdx.x * 4 + waveid;   // 0..255
    const int ubase  = W * 2;
    const int grow   = gate * HDD + ubase + unit; // gate-row index

    // weights: w_hh[grow][seg*64 .. +64) -> 16 float4 (no pin: R4 proved
    // residency is off the critical path; reloads hide under the poll wait)
    float4 w[16];
    {
        const float4* wp = (const float4*)(whh + (size_t)grow * HDD + seg * 64);
        #pragma unroll
        for (int i = 0; i < 16; ++i) w[i] = wp[i];
    }

    // per-wave padded h staging: 8 segs x 68 floats (68%32=4 -> disjoint bank
    // groups across segs; same-seg lanes broadcast). 4*544*4B = 8704 B.
    __shared__ float hsh[4 * 544];
    float* myh = hsh + waveid * 544;

    float c = c0[dir * HDD + ubase + unit];

    const int t0 = dir ? (TT - 1) : 0;
    float xvn = xg[((size_t)dir * TT + t0) * 2048 + grow];

    // armed h values for the upcoming step (step 0: from h0)
    unsigned u[8];
    #pragma unroll
    for (int j = 0; j < 8; ++j)
        u[j] = __float_as_uint(h0[dir * HDD + j * 64 + lane]);

    for (int s = 0; s < TT; ++s) {
        const int t = dir ? (TT - 1 - s) : s;
        const float xv = xvn;
        if (s + 1 < TT) {
            const int tn = dir ? (TT - 2 - s) : (s + 1);
            xvn = xg[((size_t)dir * TT + tn) * 2048 + grow];
        }

        // validate armed values; retry only still-sentinel entries
        if (s > 0) {
            const int tprev = dir ? (t + 1) : (t - 1);
            const unsigned* hsrc =
                (const unsigned*)(hs + ((size_t)dir * TT + tprev) * HDD);
            bool ok = true;
            #pragma unroll
            for (int j = 0; j < 8; ++j) ok &= (u[j] != SENT);
            while (!ok) {
                #pragma unroll
                for (int j = 0; j < 8; ++j)
                    if (u[j] == SENT)
                        u[j] = __hip_atomic_load(hsrc + j * 64 + lane,
                                __ATOMIC_RELAXED, __HIP_MEMORY_SCOPE_AGENT);
                ok = true;
                #pragma unroll
                for (int j = 0; j < 8; ++j) ok &= (u[j] != SENT);
            }
        }

        // stage to LDS: index j*64+lane -> myh[j*68 + lane] (seg j region)
        #pragma unroll
        for (int j = 0; j < 8; ++j)
            myh[j * 68 + lane] = __uint_as_float(u[j]);

        // dot over this lane's 64-float segment, 4 accumulators
        float a0 = 0.f, a1 = 0.f, a2 = 0.f, a3 = 0.f;
        const float4* hp = (const float4*)(myh + seg * 68);  // 272B: 16B-aligned
        #pragma unroll
        for (int i = 0; i < 16; i += 4) {
            float4 h0v = hp[i], h1v = hp[i+1], h2v = hp[i+2], h3v = hp[i+3];
            a0 += w[i].x*h0v.x + w[i].y*h0v.y + w[i].z*h0v.z + w[i].w*h0v.w;
            a1 += w[i+1].x*h1v.x + w[i+1].y*h1v.y + w[i+1].z*h1v.z + w[i+1].w*h1v.w;
            a2 += w[i+2].x*h2v.x + w[i+2].y*h2v.y + w[i+2].z*h2v.z + w[i+2].w*h2v.w;
            a3 += w[i+3].x*h3v.x + w[i+3].y*h3v.y + w[i+3].z*h3v.z + w[i+3].w*h3v.w;
        }
        float acc = (a0 + a1) + (a2 + a3);
        // reduce across 8 segs (xor 1,2,4 stay within DPP range -> fast)
        acc += __shfl_xor(acc, 1);
        acc += __shfl_xor(acc, 2);
        acc += __shfl_xor(acc, 4);
        acc += xv;

        // gather i,f,g,o for this lane's unit
        const int gb = (lane & ~31) + (lane & 7);
        const float iv = __shfl(acc, gb);
        const float fv = __shfl(acc, gb + 8);
        const float gv = __shfl(acc, gb + 16);
        const float ov = __shfl(acc, gb + 24);
        c = fsig(fv) * c + fsig(iv) * ftanh(gv);
        const float h = fsig(ov) * ftanh(c);

        // publish own units (2 lanes per wave)
        if ((lane & 31) == 0)
            __hip_atomic_store(&hs[((size_t)dir * TT + t) * HDD + ubase + unit], h,
                               __ATOMIC_RELAXED, __HIP_MEMORY_SCOPE_AGENT);

        // pre-arm poll for next step; substitute own units from registers
        if (s + 1 < TT) {
            const unsigned* hnow =
                (const unsigned*)(hs + ((size_t)dir * TT + t) * HDD);
            const float hu0 = __shfl(h, 0);
            const float hu1 = __shfl(h, 32);
            #pragma unroll
            for (int j = 0; j < 8; ++j) {
                unsigned val = __hip_atomic_load(hnow + j * 64 + lane,
                        __ATOMIC_RELAXED, __HIP_MEMORY_SCOPE_AGENT);
                const int g = j * 64 + lane;
                if (g == ubase)     val = __float_as_uint(hu0);
                if (g == ubase + 1) val = __float_as_uint(hu1);
                u[j] = val;
            }
        }
    }
}

// ------- feats[t][tag] = sum_k concat(hf,hb)[t][k]*W_out[tag][k] + b_out -----
__global__ __launch_bounds__(256) void k_feats(const float* __restrict__ hs,
        const float* __restrict__ Wout, const float* __restrict__ bout,
        float* __restrict__ feats) {
    const int t = blockIdx.x;
    const int tid = threadIdx.x;
    const int tag = tid >> 3;    // 0..31
    const int chunk = tid & 7;   // 8 chunks of 128 k
    const float* __restrict__ hrow = (chunk < 4)
        ? hs + (size_t)t * HDD
        : hs + ((size_t)TT + t) * HDD - 512;
    float acc = 0.f;
    const float4* wp = (const float4*)(Wout + (size_t)tag * 1024 + chunk * 128);
    const float4* hp = (const float4*)(hrow + chunk * 128);
    #pragma unroll
    for (int i = 0; i < 32; ++i) {
        float4 wv = wp[i];
        float4 hv = hp[i];
        acc += wv.x*hv.x + wv.y*hv.y + wv.z*hv.z + wv.w*hv.w;
    }
    __shared__ float red[TAGS][9];
    red[tag][chunk] = acc;
    __syncthreads();
    if (tid < TAGS) {
        float s = bout[tid];
        #pragma unroll
        for (int c = 0; c < 8; ++c) s += red[tid][c];
        feats[(size_t)t * TAGS + tid] = s;
    }
}

// ---------------- Viterbi: single wave, transitions in registers ------------
__global__ __launch_bounds__(64) void k_viterbi(const float* __restrict__ feats,
        const float* __restrict__ trans, unsigned char* __restrict__ bp8,
        float* __restrict__ out) {
    const int lane = threadIdx.x;
    const int n = lane & 31;          // both half-waves duplicate work (benign)
    __shared__ float fvs[TAGS];
    __shared__ float term[TAGS];
    __shared__ __align__(16) float fbuf[VCH * TAGS];
    float tr[TAGS];
    #pragma unroll
    for (int p = 0; p < TAGS; ++p) tr[p] = trans[n * TAGS + p];
    if (lane < TAGS) fvs[lane] = (lane == STARTT) ? 0.f : NEGV;
    __syncthreads();
    for (int c0 = 0; c0 < TT; c0 += VCH) {
        const float4* src = (const float4*)(feats + (size_t)c0 * TAGS);
        float4* dst = (float4*)fbuf;
        for (int i = lane; i < VCH * TAGS / 4; i += 64) dst[i] = src[i];
        __syncthreads();
        for (int lt = 0; lt < VCH; ++lt) {
            const int t = c0 + lt;
            float bv = fvs[0] + tr[0];
            int bi = 0;
            #pragma unroll
            for (int p = 1; p < TAGS; ++p) {
                const float cand = fvs[p] + tr[p];
                if (cand > bv) { bv = cand; bi = p; }  // strict > keeps first-max
            }
            const float nf = bv + fbuf[lt * TAGS + n];
            bp8[(size_t)t * TAGS + n] = (unsigned char)bi;
            __syncthreads();
            fvs[n] = nf;
            __syncthreads();
        }
    }
    if (lane < TAGS) term[lane] = fvs[lane] + trans[STOPP * TAGS + lane];
    __syncthreads();
    if (lane == 0) {
        float bs = term[0]; int best = 0;
        for (int i = 1; i < TAGS; ++i)
            if (term[i] > bs) { bs = term[i]; best = i; }
        out[0] = bs;
        int tag = best;
        for (int t = TT - 1; t >= 0; --t) {
            out[1 + t] = (float)tag;
            tag = bp8[(size_t)t * TAGS + tag];
        }
    }
}

extern "C" void kernel_launch(void* const* d_in, const int* in_sizes, int n_in,
                              void* d_out, int out_size, void* d_ws, size_t ws_size,
                              hipStream_t stream) {
    const int*   sent  = (const int*)  d_in[0];
    const float* emb   = (const float*)d_in[1];
    const float* wihf  = (const float*)d_in[2];
    const float* whhf  = (const float*)d_in[3];
    const float* bfv   = (const float*)d_in[4];
    const float* wihb  = (const float*)d_in[5];
    const float* whhb  = (const float*)d_in[6];
    const float* bbv   = (const float*)d_in[7];
    const float* Wout  = (const float*)d_in[8];
    const float* bout  = (const float*)d_in[9];
    const float* trans = (const float*)d_in[10];
    const float* h0    = (const float*)d_in[11];
    const float* c0    = (const float*)d_in[12];
    float* out = (float*)d_out;

    char* ws = (char*)d_ws;
    float* x     = (float*)(ws);                                  //  4 MiB
    float* xg    = (float*)(ws + ((size_t)4  << 20));             // 32 MiB  [2][T][2048]
    float* hs    = (float*)(ws + ((size_t)36 << 20));             //  8 MiB  [2][T][512]
    float* feats = (float*)(ws + ((size_t)44 << 20));             // 256 KiB [T][32]
    unsigned char* bp8 = (unsigned char*)(ws + ((size_t)44 << 20) + (256u << 10)); // 64 KiB

    // sentinel-fill hs (0xFF bytes = -NaN pattern; finite h can never equal it)
    hipMemsetAsync(hs, 0xFF, (size_t)2 * TT * HDD * sizeof(float), stream);
    k_gather <<<TT, 128, 0, stream>>>(sent, emb, x);
    k_xgemm  <<<dim3(32, 32, 2), 256, 0, stream>>>(x, wihf, wihb, bfv, bbv, xg);
    k_lstm   <<<dim3(64, 2), 256, 0, stream>>>(xg, whhf, whhb, h0, c0, hs);
    k_feats  <<<TT, 256, 0, stream>>>(hs, Wout, bout, feats);
    k_viterbi<<<1, 64, 0, stream>>>(feats, trans, bp8, out);
}

// Round 6
// 4496.030 us; speedup vs baseline: 2.2499x; 2.2499x over previous
//
#include <hip/hip_runtime.h>
#include <math.h>

#define TT 2048
#define EE 512
#define HDD 512
#define TAGS 32
#define STARTT 30
#define STOPP 31
#define NEGV -10000.0f
#define VCH 256
#define SENT 0xFFFFFFFFu   // hs sentinel: -NaN bit pattern, unreachable for finite h

// ---- xg[dir][t][n] = sum_k emb[sent[t]][k]*w_ih[n][k] + b[n], tile-flagged ----
// grid: x = n-tile (32), y = (dir,ttile) interleaved urgent-first (64).
// After a block stores its tile it release-adds flag[dir*32+ttile]; k_lstm
// acquire-polls >=32 before consuming that t-range. Runs CONCURRENT with
// k_lstm (launched first; makes progress independently -> no deadlock).
__global__ __launch_bounds__(256) void k_xgemm(const int* __restrict__ sent,
        const float* __restrict__ emb,
        const float* __restrict__ wf, const float* __restrict__ wb,
        const float* __restrict__ bf, const float* __restrict__ bb,
        float* __restrict__ xg, int* __restrict__ xflag) {
    const int jj   = blockIdx.y >> 1;
    const int dir  = blockIdx.y & 1;
    const int tile = dir ? (31 - jj) : jj;     // urgent tiles first in dispatch
    const float* __restrict__ w    = dir ? wb : wf;
    const float* __restrict__ bias = dir ? bb : bf;
    const int tb = tile * 64;
    const int nb = blockIdx.x * 64;
    __shared__ float As[64][17];
    __shared__ float Bs[64][17];
    const int tid = threadIdx.x;
    const int lr = tid >> 2;
    const int lc = (tid & 3) * 4;
    const int ty = tid >> 4;
    const int tx = tid & 15;
    const int sidx = sent[tb + lr];            // fused embedding gather
    float acc[4][4] = {};
    for (int k0 = 0; k0 < EE; k0 += 16) {
        float4 av = *(const float4*)(emb + (size_t)sidx * EE + k0 + lc);
        float4 bv = *(const float4*)(w + (size_t)(nb + lr) * EE + k0 + lc);
        As[lr][lc+0] = av.x; As[lr][lc+1] = av.y; As[lr][lc+2] = av.z; As[lr][lc+3] = av.w;
        Bs[lr][lc+0] = bv.x; Bs[lr][lc+1] = bv.y; Bs[lr][lc+2] = bv.z; Bs[lr][lc+3] = bv.w;
        __syncthreads();
        #pragma unroll
        for (int kk = 0; kk < 16; ++kk) {
            float a[4], b[4];
            #pragma unroll
            for (int i = 0; i < 4; ++i) a[i] = As[ty*4+i][kk];
            #pragma unroll
            for (int j = 0; j < 4; ++j) b[j] = Bs[tx*4+j][kk];
            #pragma unroll
            for (int i = 0; i < 4; ++i)
                #pragma unroll
                for (int j = 0; j < 4; ++j)
                    acc[i][j] += a[i] * b[j];
        }
        __syncthreads();
    }
    #pragma unroll
    for (int i = 0; i < 4; ++i) {
        float4 o;
        o.x = acc[i][0] + bias[nb + tx*4 + 0];
        o.y = acc[i][1] + bias[nb + tx*4 + 1];
        o.z = acc[i][2] + bias[nb + tx*4 + 2];
        o.w = acc[i][3] + bias[nb + tx*4 + 3];
        *(float4*)(xg + ((size_t)dir*TT + tb + ty*4 + i) * 2048 + nb + tx*4) = o;
    }
    __syncthreads();
    if (tid == 0)
        __hip_atomic_fetch_add(&xflag[dir * 32 + tile], 1,
                               __ATOMIC_RELEASE, __HIP_MEMORY_SCOPE_AGENT);
}

__device__ __forceinline__ float fsig(float x) {
    return __builtin_amdgcn_rcpf(1.f + __expf(-x));
}
__device__ __forceinline__ float ftanh(float x) {
    return 2.f * __builtin_amdgcn_rcpf(1.f + __expf(-2.f * x)) - 1.f;
}

__device__ __forceinline__ void waitflag(const int* f) {
    while (__hip_atomic_load(f, __ATOMIC_ACQUIRE, __HIP_MEMORY_SCOPE_AGENT) < 32)
        __builtin_amdgcn_s_sleep(1);
}

// ---------------- bidirectional LSTM recurrence v3 ----------------
// grid (32,2) x 256 = 128 waves/dir, R2's proven lane layout (wave owns 4
// units; lane = unit*16+gate*4+seg, 4-way k split). NEW vs R2:
//  (a) WG-SHARED double-buffered h staging: each lane polls ONE dwordx2 of
//      h (2 floats) instead of 8 dwords -> 4x less LLC poll traffic, 8x fewer
//      poll instructions; one __syncthreads/step joins the 4 waves.
//  (b) dot uses 4 independent accumulators (serial FMA chain ~128 -> ~40).
//  (c) xg is produced concurrently by k_xgemm; gated per 64-step tile via
//      acquire flags; xg read with agent-scope atomic loads (L2-stale-safe).
__global__ __launch_bounds__(256, 1) void k_lstm(const float* __restrict__ xg,
        const float* __restrict__ whhf, const float* __restrict__ whhb,
        const float* __restrict__ h0, const float* __restrict__ c0,
        float* __restrict__ hs, const int* __restrict__ xflag) {
    const int dir = blockIdx.y;
    const float* __restrict__ whh = dir ? whhb : whhf;
    const int tid    = threadIdx.x;
    const int lane   = tid & 63;
    const int waveid = tid >> 6;
    const int unit   = lane >> 4;        // 0..3
    const int gate   = (lane >> 2) & 3;  // i,f,g,o
    const int seg    = lane & 3;         // k segment (128 floats)
    const int ubase  = (blockIdx.x * 4 + waveid) * 4;
    const int grow   = gate * HDD + ubase + unit;

    float4 w[32];
    {
        const float4* wp = (const float4*)(whh + (size_t)grow * HDD + seg * 128);
        #pragma unroll
        for (int i = 0; i < 32; ++i) w[i] = wp[i];
    }

    // WG-shared, double-buffered, padded: 2 bufs x 4 segs x 132 floats
    __shared__ float hbuf[2][528];

    float c = c0[dir * HDD + ubase + unit];

    const int* flags = xflag + dir * 32;
    const int t0 = dir ? (TT - 1) : 0;
    int curtile = t0 >> 6;
    waitflag(&flags[curtile]);
    float xvn = __uint_as_float(__hip_atomic_load(
        (const unsigned*)(xg + ((size_t)dir * TT + t0) * 2048 + grow),
        __ATOMIC_RELAXED, __HIP_MEMORY_SCOPE_AGENT));

    // stage step 0's h (from h0) into buf 0: 2 consecutive floats per lane
    const int g0 = 2 * tid;
    const int soff = (g0 >> 7) * 132 + (g0 & 127);
    hbuf[0][soff]     = h0[dir * HDD + g0];
    hbuf[0][soff + 1] = h0[dir * HDD + g0 + 1];

    for (int s = 0; s < TT; ++s) {
        const int t = dir ? (TT - 1 - s) : s;
        const float xv = xvn;
        if (s + 1 < TT) {
            const int tn = dir ? (TT - 2 - s) : (s + 1);
            const int tilen = tn >> 6;
            if (tilen != curtile) { waitflag(&flags[tilen]); curtile = tilen; }
            xvn = __uint_as_float(__hip_atomic_load(
                (const unsigned*)(xg + ((size_t)dir * TT + tn) * 2048 + grow),
                __ATOMIC_RELAXED, __HIP_MEMORY_SCOPE_AGENT));
        }

        float* hb = hbuf[s & 1];
        if (s > 0) {
            const int tprev = dir ? (t + 1) : (t - 1);
            const unsigned long long* hsrc = (const unsigned long long*)
                (hs + ((size_t)dir * TT + tprev) * HDD) + tid;
            unsigned long long vv = __hip_atomic_load(hsrc,
                    __ATOMIC_RELAXED, __HIP_MEMORY_SCOPE_AGENT);
            while ((unsigned)vv == SENT || (unsigned)(vv >> 32) == SENT)
                vv = __hip_atomic_load(hsrc,
                        __ATOMIC_RELAXED, __HIP_MEMORY_SCOPE_AGENT);
            hb[soff]     = __uint_as_float((unsigned)vv);
            hb[soff + 1] = __uint_as_float((unsigned)(vv >> 32));
        }
        __syncthreads();

        // dot over this lane's 128-float segment, 4 independent accumulators
        const float4* hp = (const float4*)(hb + seg * 132);
        float a0 = 0.f, a1 = 0.f, a2 = 0.f, a3 = 0.f;
        #pragma unroll
        for (int i = 0; i < 32; i += 4) {
            float4 h0v = hp[i], h1v = hp[i+1], h2v = hp[i+2], h3v = hp[i+3];
            a0 += w[i  ].x*h0v.x + w[i  ].y*h0v.y + w[i  ].z*h0v.z + w[i  ].w*h0v.w;
            a1 += w[i+1].x*h1v.x + w[i+1].y*h1v.y + w[i+1].z*h1v.z + w[i+1].w*h1v.w;
            a2 += w[i+2].x*h2v.x + w[i+2].y*h2v.y + w[i+2].z*h2v.z + w[i+2].w*h2v.w;
            a3 += w[i+3].x*h3v.x + w[i+3].y*h3v.y + w[i+3].z*h3v.z + w[i+3].w*h3v.w;
        }
        float acc = (a0 + a1) + (a2 + a3);
        acc += __shfl_xor(acc, 1);
        acc += __shfl_xor(acc, 2);
        acc += xv;

        const int base = lane & ~15;
        const float iv = __shfl(acc, base + 0);
        const float fv = __shfl(acc, base + 4);
        const float gv = __shfl(acc, base + 8);
        const float ov = __shfl(acc, base + 12);
        c = fsig(fv) * c + fsig(iv) * ftanh(gv);
        const float h = fsig(ov) * ftanh(c);

        if ((lane & 15) == 0)
            __hip_atomic_store(&hs[((size_t)dir * TT + t) * HDD + ubase + unit], h,
                               __ATOMIC_RELAXED, __HIP_MEMORY_SCOPE_AGENT);
    }
}

// ------- feats[t][tag] = sum_k concat(hf,hb)[t][k]*W_out[tag][k] + b_out -----
__global__ __launch_bounds__(256) void k_feats(const float* __restrict__ hs,
        const float* __restrict__ Wout, const float* __restrict__ bout,
        float* __restrict__ feats) {
    const int t = blockIdx.x;
    const int tid = threadIdx.x;
    const int tag = tid >> 3;
    const int chunk = tid & 7;
    const float* __restrict__ hrow = (chunk < 4)
        ? hs + (size_t)t * HDD
        : hs + ((size_t)TT + t) * HDD - 512;
    float acc = 0.f;
    const float4* wp = (const float4*)(Wout + (size_t)tag * 1024 + chunk * 128);
    const float4* hp = (const float4*)(hrow + chunk * 128);
    #pragma unroll
    for (int i = 0; i < 32; ++i) {
        float4 wv = wp[i];
        float4 hv = hp[i];
        acc += wv.x*hv.x + wv.y*hv.y + wv.z*hv.z + wv.w*hv.w;
    }
    __shared__ float red[TAGS][9];
    red[tag][chunk] = acc;
    __syncthreads();
    if (tid < TAGS) {
        float s = bout[tid];
        #pragma unroll
        for (int c = 0; c < 8; ++c) s += red[tid][c];
        feats[(size_t)t * TAGS + tid] = s;
    }
}

// ------- Viterbi: single wave; bp in LDS; 2-way prev split per tag ---------
__global__ __launch_bounds__(64) void k_viterbi(const float* __restrict__ feats,
        const float* __restrict__ trans, float* __restrict__ out) {
    const int lane = threadIdx.x;
    const int n  = lane & 31;   // next tag
    const int ph = lane >> 5;   // prev half (0: prevs 0-15, 1: prevs 16-31)
    __shared__ float fvs[TAGS];
    __shared__ unsigned char bp[TT][TAGS];            // 64 KiB, on-chip backtrack
    __shared__ __align__(16) float fbuf[VCH * TAGS];  // 32 KiB feats chunk
    float tr[16];
    #pragma unroll
    for (int p = 0; p < 16; ++p) tr[p] = trans[n * TAGS + ph * 16 + p];
    if (lane < TAGS) fvs[lane] = (lane == STARTT) ? 0.f : NEGV;
    __syncthreads();
    for (int c0 = 0; c0 < TT; c0 += VCH) {
        const float4* src = (const float4*)(feats + (size_t)c0 * TAGS);
        float4* dst = (float4*)fbuf;
        for (int i = lane; i < VCH * TAGS / 4; i += 64) dst[i] = src[i];
        __syncthreads();
        for (int lt = 0; lt < VCH; ++lt) {
            const int t = c0 + lt;
            float bv = fvs[ph * 16] + tr[0];
            int bi = ph * 16;
            #pragma unroll
            for (int p = 1; p < 16; ++p) {
                const float cand = fvs[ph * 16 + p] + tr[p];
                if (cand > bv) { bv = cand; bi = ph * 16 + p; }  // first-max
            }
            // combine halves; tie -> lower prev index (np.argmax semantics)
            const float obv = __shfl_xor(bv, 32);
            const int   obi = __shfl_xor(bi, 32);
            if (obv > bv || (obv == bv && obi < bi)) { bv = obv; bi = obi; }
            const float nf = bv + fbuf[lt * TAGS + n];
            if (ph == 0) bp[t][n] = (unsigned char)bi;
            __syncthreads();
            if (ph == 0) fvs[n] = nf;
            __syncthreads();
        }
    }
    if (lane < TAGS) fvs[lane] += trans[STOPP * TAGS + lane];
    __syncthreads();
    if (lane == 0) {
        float bs = fvs[0]; int best = 0;
        for (int i = 1; i < TAGS; ++i)
            if (fvs[i] > bs) { bs = fvs[i]; best = i; }
        out[0] = bs;
        int tag = best;
        for (int t = TT - 1; t >= 0; --t) {
            out[1 + t] = (float)tag;
            tag = bp[t][tag];
        }
    }
}

extern "C" void kernel_launch(void* const* d_in, const int* in_sizes, int n_in,
                              void* d_out, int out_size, void* d_ws, size_t ws_size,
                              hipStream_t stream) {
    const int*   sent  = (const int*)  d_in[0];
    const float* emb   = (const float*)d_in[1];
    const float* wihf  = (const float*)d_in[2];
    const float* whhf  = (const float*)d_in[3];
    const float* bfv   = (const float*)d_in[4];
    const float* wihb  = (const float*)d_in[5];
    const float* whhb  = (const float*)d_in[6];
    const float* bbv   = (const float*)d_in[7];
    const float* Wout  = (const float*)d_in[8];
    const float* bout  = (const float*)d_in[9];
    const float* trans = (const float*)d_in[10];
    const float* h0    = (const float*)d_in[11];
    const float* c0    = (const float*)d_in[12];
    float* out = (float*)d_out;

    char* ws = (char*)d_ws;
    float* xg    = (float*)(ws + ((size_t)4  << 20));             // 32 MiB [2][T][2048]
    float* hs    = (float*)(ws + ((size_t)36 << 20));             //  8 MiB [2][T][512]
    float* feats = (float*)(ws + ((size_t)44 << 20));             // 256 KiB
    int* xflag   = (int*)  (ws + ((size_t)44 << 20) + (320u << 10)); // 64 ints

    hipMemsetAsync(hs, 0xFF, (size_t)2 * TT * HDD * sizeof(float), stream);
    hipMemsetAsync(xflag, 0, 64 * sizeof(int), stream);
    k_xgemm  <<<dim3(32, 64), 256, 0, stream>>>(sent, emb, wihf, wihb, bfv, bbv,
                                                xg, xflag);
    k_lstm   <<<dim3(32, 2), 256, 0, stream>>>(xg, whhf, whhb, h0, c0, hs, xflag);
    k_feats  <<<TT, 256, 0, stream>>>(hs, Wout, bout, feats);
    k_viterbi<<<1, 64, 0, stream>>>(feats, trans, out);
}